// Round 16
// baseline (148.389 us; speedup 1.0000x reference)
//
#include <hip/hip_runtime.h>

// LSTM: HIDDEN=128, SEQ=7, BATCH=65536. fp32 in/out.
//
// R23: balance + scheduler round on R22 (92.8us best).
//  * Distributed MFMA-pred: pred GEMM's 16 MFMAs (2mt x 4kk x hi/lo)
//    spread 2-per-wave (wave w -> mt=w&1, kk=w>>1) using additivity of
//    ap over kk. Partials -> predp LDS (1 b128/wave/t), summed+stored by
//    32 lanes one t later (drain at t stores out[t-2]; pred(5) drained
//    post-loop; pred(6) via old direct tail GEMM). Removes the 2-wave
//    critical-path imbalance (+8 MFMA/+8 LDS reads/+4 stores) that every
//    per-t barrier waited on.
//  * s_setprio(1) around the MFMA cluster (T5: 2 blocks/CU at
//    independent phases -> scheduler can favor GEMM-phase waves).
// Unchanged from R22: (512,4), BT=32, bw AGPR-stationary, Tw/Tb LDS,
// packed pk-fma acc-init, packed exp2 fused-reciprocal epilogue,
// cvt_pkrtz h-staging, 1 barrier/t.

#define SEQ 7
#define BT 32

typedef _Float16 half8 __attribute__((ext_vector_type(8)));
typedef __fp16 fp16x2 __attribute__((ext_vector_type(2)));
typedef float floatx4 __attribute__((ext_vector_type(4)));
typedef float floatx2 __attribute__((ext_vector_type(2)));

__device__ __forceinline__ floatx4 mfma16(half8 a, half8 b, floatx4 c) {
  return __builtin_amdgcn_mfma_f32_16x16x32_f16(a, b, c, 0, 0, 0);
}

#define LOG2E 1.4426950408889634f
#define K2 2.885390081777927f  // 2*log2e

__device__ __forceinline__ floatx2 pexp2m(floatx2 v) {
  floatx2 r;
  r.x = __builtin_amdgcn_exp2f(-v.x);
  r.y = __builtin_amdgcn_exp2f(-v.y);
  return r;
}
__device__ __forceinline__ floatx2 prcp(floatx2 v) {
  floatx2 r;
  r.x = __builtin_amdgcn_rcpf(v.x);
  r.y = __builtin_amdgcn_rcpf(v.y);
  return r;
}

// Pack W_hh [512][128] fp32 -> B-fragment-major fp16, prescaled (idx<65536):
//   Bp[((nt*4+kk)*64 + lane)*8 + jj] = S(g) * Whh[j][k]
//   nt=g*8+w, j=g*128+w*16+col, k=32kk+8quad+jj.
// idx in [65536, 69632): W_out hi/lo fragments, col-0-only 16-col tile.
__global__ void pack_kernel(const float* __restrict__ Whh,
                            const float* __restrict__ Wout,
                            _Float16* __restrict__ Bp) {
  int idx = blockIdx.x * 256 + threadIdx.x;  // 0..69631
  if (idx < 65536) {
    int jj = idx & 7;
    int lane = (idx >> 3) & 63;
    int kk = (idx >> 9) & 3;
    int nt = idx >> 11;  // 0..31
    int g = nt >> 3, w = nt & 7;
    int col = lane & 15, quad = lane >> 4;
    int j = g * 128 + w * 16 + col;
    int k = 32 * kk + 8 * quad + jj;
    float S = (g == 2) ? K2 : LOG2E;
    Bp[idx] = (_Float16)(S * Whh[j * 128 + k]);
  } else {
    int pos = idx - 65536;  // 0..4095
    int hl = pos >> 11;     // 0 = hi, 1 = lo
    int e = pos & 2047;
    int jj = e & 7;
    int lane = (e >> 3) & 63;
    int kk = e >> 9;
    int col = lane & 15, quad = lane >> 4;
    int k = 32 * kk + 8 * quad + jj;
    float wv = Wout[k];
    _Float16 hi = (_Float16)wv;
    _Float16 v = hl ? (_Float16)(wv - (float)hi) : hi;
    Bp[idx] = (col == 0) ? v : (_Float16)0.0f;
  }
}

__launch_bounds__(512, 4)
__global__ void lstm_kernel(const float* __restrict__ x,
                            const float* __restrict__ x0,
                            const float* __restrict__ Wih,
                            const float* __restrict__ bih,
                            const float* __restrict__ bhh,
                            const float* __restrict__ boutp,
                            const _Float16* __restrict__ Bp,
                            float* __restrict__ out) {
  // h staged fp16, double-buffered, 272B row stride (+8 pad).
  __shared__ _Float16 Ah[2][BT][136];  // 17,408 B
  __shared__ float xs[2][BT];          // 256 B
  __shared__ _Float16 Wo[4096];        // 8 KB W_out hi/lo B-fragments
  __shared__ floatx4 Tw[8][16];        // 2 KB prescaled wih per (w,col)
  __shared__ floatx4 Tb[8][16];        // 2 KB prescaled bias per (w,col)
  __shared__ floatx4 predp[2][2][4][4];  // 1 KB pred partials [buf][mt][kk][quad]

  const int tid = threadIdx.x;
  const int w = tid >> 6;  // wave 0..7: owns hcols [16w, 16w+16)
  const int lane = tid & 63;
  const int col = lane & 15;
  const int quad = lane >> 4;
  const int rowbase = blockIdx.x * BT;
  const int mt_p = w & 1;  // pred assignment: this wave's mt
  const int kp = w >> 1;   // pred assignment: this wave's kk

  // stage W_out fragments into LDS (512 x 16B)
  ((half8*)Wo)[tid] = ((const half8*)(Bp + 65536))[tid];

  // build per-(w,col) prescaled wih/bias tables (16B entries)
  if (tid < 128) {
    int tw = tid >> 4, tc = tid & 15;
    float* pw = (float*)&Tw[tw][tc];
    float* pb = (float*)&Tb[tw][tc];
#pragma unroll
    for (int g = 0; g < 4; ++g) {
      int j = g * 128 + tw * 16 + tc;
      float S = (g == 2) ? K2 : LOG2E;
      pw[g] = S * Wih[j];
      pb[g] = S * (bih[j] + bhh[j]);
    }
  }

  // Gate-GEMM weight fragments: 64 regs (AGPR), loaded once.
  half8 bw[4][4];
#pragma unroll
  for (int g = 0; g < 4; ++g)
#pragma unroll
    for (int kk = 0; kk < 4; ++kk)
      bw[g][kk] =
          *(const half8*)(Bp + (((g * 8 + w) * 4 + kk) * 64 + lane) * 8);

  const float bout = boutp[0];

  // Scaled cell state c~ = 2log2e*c, pair-major float2 -> 8 registers.
  floatx2 c2[2][2];
#pragma unroll
  for (int mt = 0; mt < 2; ++mt)
#pragma unroll
    for (int p = 0; p < 2; ++p) c2[mt][p] = (floatx2){0.f, 0.f};

  if (tid < BT) xs[0][tid] = x0[rowbase + tid];  // t=0 consumes x0
  __syncthreads();

#pragma unroll 1
  for (int t = 0; t < SEQ; ++t) {
    const int cur = t & 1, nxt = cur ^ 1;

    // drain pred(t-2): partials written at t-1 (into predp[cur^1]).
    if (t >= 2 && tid < 32) {
      const int pm = tid >> 4, pr = tid & 15;
      const float* pp = (const float*)&predp[cur ^ 1][pm][0][0];
      float s = pp[pr] + pp[16 + pr] + pp[32 + pr] + pp[48 + pr] + bout;
      out[(size_t)(rowbase + pm * 16 + pr) * 7 + (t - 2)] = s;
    }
    // prefetch input for t+1 (consumes x[:, t])
    if (t + 1 < SEQ && tid < BT) {
      xs[nxt][tid] = x[(size_t)(rowbase + tid) * 7 + t];
    }

#pragma unroll
    for (int mt = 0; mt < 2; ++mt) {
      // x for the 4 rows (mt*16 + quad*4 + r) this lane covers.
      floatx4 xq = *(const floatx4*)&xs[cur][mt * 16 + quad * 4];

      // wih/bias from LDS, volatile so they stay transient (no re-hoist).
      floatx4 wihv = *(volatile const floatx4*)&Tw[w][col];
      floatx4 biasv = *(volatile const floatx4*)&Tb[w][col];

      // acc init = x*W_ih + bias, PACKED (v_pk_fma_f32).
      floatx4 acc[4];
#pragma unroll
      for (int g = 0; g < 4; ++g) acc[g] = xq * wihv[g] + biasv[g];

      if (t != 0) {  // h(0)=0: skip GEMM at t=0
        floatx4 ap = (floatx4){0.f, 0.f, 0.f, 0.f};
        const bool dop = (mt == mt_p);  // wave-uniform
        __builtin_amdgcn_s_setprio(1);
#pragma unroll
        for (int kk = 0; kk < 4; ++kk) {
          half8 ah =
              *(const half8*)&Ah[cur][mt * 16 + col][kk * 32 + quad * 8];
#pragma unroll
          for (int g = 0; g < 4; ++g) acc[g] = mfma16(ah, bw[g][kk], acc[g]);
          if (dop && kk == kp) {  // this wave's 2 pred-MFMAs (additive kk)
            half8 bo0 = *(const half8*)&Wo[(kk * 64 + lane) * 8];
            half8 bo1 = *(const half8*)&Wo[2048 + (kk * 64 + lane) * 8];
            ap = mfma16(ah, bo0, ap);
            ap = mfma16(ah, bo1, ap);
          }
        }
        __builtin_amdgcn_s_setprio(0);
        if (dop && col == 0) predp[cur][mt_p][kp][quad] = ap;  // b128
      }

      // Fused-reciprocal cell update, PACKED pairs (r01, r23).
      const floatx2 one2 = {1.0f, 1.0f};
      const floatx2 k22 = {K2, K2};
#pragma unroll
      for (int p = 0; p < 2; ++p) {
        floatx2 Gi, Gf, Gg, Go;
        Gi.x = acc[0][2 * p];
        Gi.y = acc[0][2 * p + 1];
        Gf.x = acc[1][2 * p];
        Gf.y = acc[1][2 * p + 1];
        Gg.x = acc[2][2 * p];
        Gg.y = acc[2][2 * p + 1];
        Go.x = acc[3][2 * p];
        Go.y = acc[3][2 * p + 1];
        floatx2 A = pexp2m(Gi);
        floatx2 Bv = pexp2m(Gf);
        floatx2 Cv = pexp2m(Gg);
        floatx2 Dv = pexp2m(Go);
        floatx2 a1 = A + one2;
        floatx2 b1 = Bv + one2;
        floatx2 c1 = Cv + one2;
        floatx2 ac = a1 * c1;
        floatx2 t1 = k22 - Cv * k22;
        floatx2 num = c2[mt][p] * ac + t1 * b1;
        floatx2 den = ac * b1;
        floatx2 cn = num * prcp(den);
        c2[mt][p] = cn;
        floatx2 E = pexp2m(cn);
        floatx2 de = (Dv + one2) * (E + one2);
        floatx2 hn = (one2 - E) * prcp(de);

        // stage h_new: one packed cvt (RTZ), two b16 stores.
        fp16x2 hp = __builtin_amdgcn_cvt_pkrtz(hn.x, hn.y);
        const int rbase = mt * 16 + quad * 4 + 2 * p;
        Ah[nxt][rbase][w * 16 + col] = (_Float16)hp.x;
        Ah[nxt][rbase + 1][w * 16 + col] = (_Float16)hp.y;
      }
    }
    // single barrier per t: h staging + predp + xs prefetch complete
    __syncthreads();
  }

  // post-loop: drain pred(5) (partials written at t=6 into predp[0])
  if (tid < 32) {
    const int pm = tid >> 4, pr = tid & 15;
    const float* pp = (const float*)&predp[0][pm][0][0];
    float s = pp[pr] + pp[16 + pr] + pp[32 + pr] + pp[48 + pr] + bout;
    out[(size_t)(rowbase + pm * 16 + pr) * 7 + 5] = s;
  }

  // tail: pred(6) from h(6) staged in Ah[SEQ&1] (= Ah[1]), direct GEMM
  if (w < 2) {
    const int mt = w;
    floatx4 ap = (floatx4){0.f, 0.f, 0.f, 0.f};
#pragma unroll
    for (int kk = 0; kk < 4; ++kk) {
      half8 ah = *(const half8*)&Ah[1][mt * 16 + col][kk * 32 + quad * 8];
      half8 bo0 = *(const half8*)&Wo[(kk * 64 + lane) * 8];
      half8 bo1 = *(const half8*)&Wo[2048 + (kk * 64 + lane) * 8];
      ap = mfma16(ah, bo0, ap);
      ap = mfma16(ah, bo1, ap);
    }
    if (col == 0) {
#pragma unroll
      for (int r = 0; r < 4; ++r)
        out[(size_t)(rowbase + mt * 16 + quad * 4 + r) * 7 + 6] =
            ap[r] + bout;
    }
  }
}

extern "C" void kernel_launch(void* const* d_in, const int* in_sizes, int n_in,
                              void* d_out, int out_size, void* d_ws,
                              size_t ws_size, hipStream_t stream) {
  const float* x = (const float*)d_in[0];
  const float* x0 = (const float*)d_in[1];
  const float* Wih = (const float*)d_in[2];
  const float* Whh = (const float*)d_in[3];
  const float* bih = (const float*)d_in[4];
  const float* bhh = (const float*)d_in[5];
  const float* Wout = (const float*)d_in[6];
  const float* bout = (const float*)d_in[7];
  float* out = (float*)d_out;
  _Float16* Bp = (_Float16*)d_ws;  // 136 KB packed weights + wout frags

  pack_kernel<<<272, 256, 0, stream>>>(Whh, Wout, Bp);
  lstm_kernel<<<65536 / BT, 512, 0, stream>>>(x, x0, Wih, bih, bhh, bout, Bp,
                                              out);
}